// Round 16
// baseline (126.893 us; speedup 1.0000x reference)
//
#include <hip/hip_runtime.h>
#include <math.h>

// ShadowMapping forward: hard + soft shadow maps.
// R16: force-emitted load batching. R15's phase-C batching was provably
//      sunk by the allocator (VGPR=24 < the ~50 needed to hold 20 taps).
//      Fix: (a) NO divergent branches around loads — live gating removed,
//      loads unconditional (u,v always valid; mk* zeroes dead outputs
//      exactly); (b) loads in 3 straight-line clusters behind block-uniform
//      s_cbranch only (4x zg; 8x side-taps per ftap light) — uniform
//      branches don't drain vmcnt, so ~20 loads stay in flight into phase D.
//      Numerics byte-identical to R13..R15 (w1<0.0056 1-tap, plus-stencil,
//      poly-sin, geometry chain). Model: kernel = 37us latency intercept +
//      1.37us/M scattered lanes (R6..R15 fit); this attacks the intercept.

#define RESN 512
#define NL 16
#define NPIX (RESN*RESN)

__global__ void setup_kernel(const float* __restrict__ als,
                             float* __restrict__ lp) {
  #pragma clang fp contract(off)
  int l = (int)threadIdx.x;
  if (l >= NL) return;
  float xd = als[l*7+0], yd = als[l*7+1], zd = als[l*7+2], sg = als[l*7+3];
  float cosp = sqrtf(xd*xd + zd*zd);
  float cost = zd / cosp;
  float sint = xd / cosp;
  float* o = lp + l*16;
  o[0] = cost;               // e00
  o[1] = -sint;              // e02
  o[2] = (-sint)*yd;         // e10
  o[3] = cosp;               // e11
  o[4] = (-cost)*yd;         // e12
  o[5] = cosp*sint;          // e20
  o[6] = yd;                 // e21
  o[7] = cosp*cost;          // e22
  // radius-1 Gaussian, normalized over the full 21-tap sum (validated R6)
  float sig = ((2.0f*(6.0f*sg + 1.0f)) - 1.0f) / 6.0f;
  float ivs = 1.0f/(sig*sig);
  float e1  = __builtin_amdgcn_exp2f(-0.72134752044448170368f*ivs);
  float e1sq = e1*e1;
  float e2  = e1sq*e1sq;
  float kinv = 1.0f/(1.0f + 2.0f*e1 + 2.0f*e2);
  float w1n = e1*kinv;
  o[8] = kinv;               // w0
  o[9] = w1n;                // w1
  o[10] = (w1n >= 0.0056f) ? 1.0f : 0.0f;      // 5-tap mode flag
  o[11] = kinv*kinv;         // w0^2 (1-tap path)
  o[12] = o[13] = o[14] = o[15] = 0.0f;
}

__global__ __launch_bounds__(256) void fused_kernel(
    const float* __restrict__ depth,
    const float* __restrict__ mask,
    const float* __restrict__ z_map,
    const float* __restrict__ lp,
    float* __restrict__ out,
    float TANHF, float OZF, float OWF)
{
  #pragma clang fp contract(off)
  const float OFFS = -0.0642233295781f;
  const float CLB  = 0.4458709375254f;
  const float TWO_OVER_PI = 0.63661977236758134308f;
  // 4096 blocks: id&7 = light pair (l, l+8) — XCD affinity; id>>3 = row.
  // Thread handles columns c and c+256 of that row (2 pixels x 2 lights).
  const int id = (int)blockIdx.x;
  const int l0 = id & 7;
  const int r  = id >> 3;
  const int tid = (int)threadIdx.x;
  const float m1r = 2.0f * ((float)r / 512.0f + 0.0009765625f) - 1.0f;

  // per-light uniforms (block-uniform scalar loads; setup did the VALU math)
  float e00[2], e02[2], e10[2], e11[2], e12[2], e20[2], e21[2], e22[2];
  float w0c[2], w1c[2], w0sq[2];
  bool ftap[2];
  #pragma unroll
  for (int k = 0; k < 2; ++k) {
    const float* P = lp + (l0 + (k<<3))*16;
    e00[k]=P[0]; e02[k]=P[1]; e10[k]=P[2]; e11[k]=P[3]; e12[k]=P[4];
    e20[k]=P[5]; e21[k]=P[6]; e22[k]=P[7];
    w0c[k]=P[8]; w1c[k]=P[9]; ftap[k]=P[10]!=0.0f; w0sq[k]=P[11];
  }

  // ---- phase A: coalesced input loads ------------------------------------
  int C[2];  C[0] = tid;  C[1] = tid + 256;
  int Pp[2]; Pp[0] = (r<<9) + C[0]; Pp[1] = (r<<9) + C[1];
  float dzv[2], mkv[2];
  dzv[0] = depth[Pp[0]]; dzv[1] = depth[Pp[1]];
  mkv[0] = mask[Pp[0]];  mkv[1] = mask[Pp[1]];

  // ---- phase B: geometry x4 (VALU only; validated fmuladd chain) ---------
  int U[2][2], V[2][2];
  float DD[2][2], DPO[2][2];
  #pragma unroll
  for (int i = 0; i < 2; ++i) {
    float dz = dzv[i];
    float m1c = 2.0f * ((float)C[i] / 512.0f + 0.0009765625f) - 1.0f;
    float tT = dz * TANHF;
    float qx = tT * m1c;
    float qy = tT * m1r;
    float qz = 2.7f - dz;
    #pragma unroll
    for (int k = 0; k < 2; ++k) {
      float X1 = fmaf(qz, e02[k], qx * e00[k]);
      float Y1 = fmaf(qz, e12[k], fmaf(qy, e11[k], qx * e10[k]));
      float T2 = fmaf(qz, e22[k], fmaf(qy, e21[k], qx * e20[k]));
      float Z1 = T2 + (-2.7f);
      float ZZ = (Z1 * OZF) + OWF;
      float uf = (X1 + 1.0f) * 256.0f;
      float vf = (Y1 + 1.0f) * 256.0f;
      int u = (int)uf; u = u < 0 ? 0 : (u > 511 ? 511 : u);
      int v = (int)vf; v = v < 0 ? 0 : (v > 511 ? 511 : v);
      float dd = 0.5f * (1.0f + ZZ);
      dd = fminf(fmaxf(dd, 0.0f), 1.0f);
      U[i][k] = u; V[i][k] = v; DD[i][k] = dd; DPO[i][k] = dd + OFFS;
    }
  }

  // ---- phase C: straight-line load clusters (no divergent branches) ------
  // cluster 1: 4 unconditional zg loads
  float ZG[2][2];
  #pragma unroll
  for (int i = 0; i < 2; ++i)
    #pragma unroll
    for (int k = 0; k < 2; ++k)
      ZG[i][k] = z_map[((l0 + (k<<3)) << 18) + (V[i][k] << 9) + U[i][k]];
  // clusters 2,3: side taps per ftap light (block-uniform s_cbranch only)
  float ZT[2][2], ZL[2][2], ZR[2][2], ZB[2][2];
  #pragma unroll
  for (int k = 0; k < 2; ++k) {
    if (ftap[k]) {
      #pragma unroll
      for (int i = 0; i < 2; ++i) {
        const int base = (l0 + (k<<3)) << 18;
        int u = U[i][k], v = V[i][k];
        int u0 = u > 0 ? u - 1 : 0;
        int u2 = u < 511 ? u + 1 : 511;
        int v0 = v > 0 ? v - 1 : 0;
        int v2 = v < 511 ? v + 1 : 511;
        const float* zrC = z_map + base + (v << 9);
        ZT[i][k] = z_map[base + (v0 << 9) + u];
        ZL[i][k] = zrC[u0];
        ZR[i][k] = zrC[u2];
        ZB[i][k] = z_map[base + (v2 << 9) + u];
      }
    }
  }

  // ---- phase D: poly + outputs (mk* zeroes dead pixels exactly) ----------
  #pragma unroll
  for (int i = 0; i < 2; ++i) {
    #pragma unroll
    for (int k = 0; k < 2; ++k) {
      const int base = (l0 + (k<<3)) << 18;
      float dpo = DPO[i][k];
      // f = sum_{m odd<=7} (1/m) sin(m*pi*(z-dpo)) = s*P(s^2)
      auto fval = [&](float z) {
        float s = __builtin_amdgcn_sinf(0.5f * (z - dpo));   // revolutions
        float t = s * s;
        return s * fmaf(t, fmaf(t, fmaf(t, -9.142857142857142f, 19.2f),
                                -13.333333333333334f), 4.0f);
      };
      float zg = ZG[i][k];
      float q;
      if (ftap[k]) {
        int u = U[i][k], v = V[i][k];
        float w1 = w1c[k];
        float wuL = (u > 0)   ? w1 : 0.0f;
        float wuR = (u < 511) ? w1 : 0.0f;
        float wvT = (v > 0)   ? w1 : 0.0f;
        float wvB = (v < 511) ? w1 : 0.0f;
        float qs = w0c[k] * fval(zg);
        qs = fmaf(wvT, fval(ZT[i][k]), qs);
        qs = fmaf(wvB, fval(ZB[i][k]), qs);
        qs = fmaf(wuL, fval(ZL[i][k]), qs);
        qs = fmaf(wuR, fval(ZR[i][k]), qs);
        q = TWO_OVER_PI * (w0c[k] * qs);
      } else {
        // 1-tap mode: side weights < 5.6e-3 dropped (validated R13)
        q = TWO_OVER_PI * (w0sq[k] * fval(zg));
      }
      float diff = fmaxf(DD[i][k] - zg, 0.0f);
      float hard_out = mkv[i] * ((diff > 0.008f) ? 0.0f : 1.0f);
      float qc = fminf(fmaxf(q, -CLB), CLB) / CLB;
      float sf = 0.5f * (qc + 1.0f);
      float soft_out = mkv[i] * fminf(fmaxf(sf, 0.0f), 1.0f);
      out[base + Pp[i]] = hard_out;
      out[(NL*NPIX) + base + Pp[i]] = soft_out;
    }
  }
}

extern "C" void kernel_launch(void* const* d_in, const int* in_sizes, int n_in,
                              void* d_out, int out_size, void* d_ws, size_t ws_size,
                              hipStream_t stream) {
  (void)in_sizes; (void)n_in; (void)out_size; (void)ws_size;
  const float* depth = (const float*)d_in[0];
  const float* als   = (const float*)d_in[1];
  const float* mask  = (const float*)d_in[2];
  const float* z_map = (const float*)d_in[3];
  float* out = (float*)d_out;
  float* lp = (float*)d_ws;                       // 16 lights x 16 floats = 1KB
  // constants in double, replicating numpy, then rounded to f32
  double TANH = tan(2.0*atan(0.5*36.0/50.0)/2.0);
  double NEARc = 2.7 - sqrt(2.0)*2.7*TANH;
  double FARc  = 2.7 + sqrt(2.0)*2.7*TANH;
  float ozf = (float)(-2.0/(FARc-NEARc));
  float owf = (float)((-(FARc+NEARc))/(FARc-NEARc));
  float tanhf_ = (float)TANH;

  setup_kernel<<<1, 64, 0, stream>>>(als, lp);
  // 4096 blocks x 256 thr: 2 half-row pixels x 2 lights per thread
  fused_kernel<<<(NL/2)*RESN, 256, 0, stream>>>(depth, mask, z_map, lp,
                                                out, tanhf_, ozf, owf);
}

// Round 17
// 113.633 us; speedup vs baseline: 1.1167x; 1.1167x over previous
//
#include <hip/hip_runtime.h>
#include <math.h>

// ShadowMapping forward: hard + soft shadow maps.
// R17 = R14 revert (measured session optimum: 114.6us total, ~49us kernel).
//      R16's batching experiment regressed (+9us): allocator re-sunk the tap
//      batch (VGPR 28, needed ~50) and un-gated masks cost +20% scattered
//      lanes. Config: 128-thr blocks, grid 16384, 2 lights/thread (l, l+8
//      XCD affinity), mask gating, w1<0.0056 1-tap mode, 5-tap plus-stencil,
//      poly-sin identity, setup kernel for per-light uniforms.
//      Validated chain: geometry fmuladd (R2), 3x3->plus blur (R6/R9),
//      poly-sin (R7), setup offload (R11), mask gating + threshold (R13).

#define RESN 512
#define NL 16
#define NPIX (RESN*RESN)

__global__ void setup_kernel(const float* __restrict__ als,
                             float* __restrict__ lp) {
  #pragma clang fp contract(off)
  int l = (int)threadIdx.x;
  if (l >= NL) return;
  float xd = als[l*7+0], yd = als[l*7+1], zd = als[l*7+2], sg = als[l*7+3];
  float cosp = sqrtf(xd*xd + zd*zd);
  float cost = zd / cosp;
  float sint = xd / cosp;
  float* o = lp + l*16;
  o[0] = cost;               // e00
  o[1] = -sint;              // e02
  o[2] = (-sint)*yd;         // e10
  o[3] = cosp;               // e11
  o[4] = (-cost)*yd;         // e12
  o[5] = cosp*sint;          // e20
  o[6] = yd;                 // e21
  o[7] = cosp*cost;          // e22
  // radius-1 Gaussian, normalized over the full 21-tap sum (validated R6)
  float sig = ((2.0f*(6.0f*sg + 1.0f)) - 1.0f) / 6.0f;
  float ivs = 1.0f/(sig*sig);
  float e1  = __builtin_amdgcn_exp2f(-0.72134752044448170368f*ivs);
  float e1sq = e1*e1;
  float e2  = e1sq*e1sq;
  float kinv = 1.0f/(1.0f + 2.0f*e1 + 2.0f*e2);
  float w1n = e1*kinv;
  o[8] = kinv;               // w0
  o[9] = w1n;                // w1
  // side-tap worst-case sf delta = (2/pi)*w0*4*w1n*0.93 <= 0.0115 at cutoff
  o[10] = (w1n >= 0.0056f) ? 1.0f : 0.0f;      // 5-tap mode flag
  o[11] = kinv*kinv;         // w0^2 (1-tap path)
  o[12] = o[13] = o[14] = o[15] = 0.0f;
}

__global__ __launch_bounds__(128) void fused_kernel(
    const float* __restrict__ depth,
    const float* __restrict__ mask,
    const float* __restrict__ z_map,
    const float* __restrict__ lp,
    float* __restrict__ out,
    float TANHF, float OZF, float OWF)
{
  #pragma clang fp contract(off)
  const float OFFS = -0.0642233295781f;
  const float CLB  = 0.4458709375254f;
  const float TWO_OVER_PI = 0.63661977236758134308f;
  // 16384 blocks: id&7 = light pair (l, l+8) — XCD affinity;
  // id>>3 in [0,2048) = 128-px block (quarter row).
  const int id = (int)blockIdx.x;
  const int l0 = id & 7;
  const int p  = ((id >> 3) << 7) + (int)threadIdx.x;
  const int r  = p >> 9, c = p & 511;

  float dz = depth[p];
  float mk = mask[p];
  float m1c = 2.0f * ((float)c / 512.0f + 0.0009765625f) - 1.0f;
  float m1r = 2.0f * ((float)r / 512.0f + 0.0009765625f) - 1.0f;
  float tT = dz * TANHF;
  float qx = tT * m1c;
  float qy = tT * m1r;
  float qz = 2.7f - dz;
  const bool live = (mk != 0.0f);

  #pragma unroll
  for (int k = 0; k < 2; ++k) {
    const int l = l0 + (k << 3);
    const int base = l << 18;
    float hard_out = 0.0f, soft_out = 0.0f;
    if (live) {
      const float* P = lp + l*16;     // block-uniform -> scalar loads
      float e00 = P[0], e02 = P[1], e10 = P[2], e11 = P[3], e12 = P[4];
      float e20 = P[5], e21 = P[6], e22 = P[7];
      float w0 = P[8], w1 = P[9];
      bool five_tap = P[10] != 0.0f;
      float w0sq = P[11];

      // XLA dot emitter: sequential fmuladd over w (validated R2)
      float X1 = fmaf(qz, e02, qx * e00);
      float Y1 = fmaf(qz, e12, fmaf(qy, e11, qx * e10));
      float T2 = fmaf(qz, e22, fmaf(qy, e21, qx * e20));
      float Z1 = T2 + (-2.7f);
      float ZZ = (Z1 * OZF) + OWF;
      float uf = (X1 + 1.0f) * 256.0f;
      float vf = (Y1 + 1.0f) * 256.0f;
      int u = (int)uf; u = u < 0 ? 0 : (u > 511 ? 511 : u);
      int v = (int)vf; v = v < 0 ? 0 : (v > 511 ? 511 : v);
      float dd = 0.5f * (1.0f + ZZ);
      dd = fminf(fmaxf(dd, 0.0f), 1.0f);
      float dpo = dd + OFFS;

      const float* zrC = z_map + base + (v << 9);
      float zg = zrC[u];

      // f = sum_{m odd<=7} (1/m) sin(m*pi*(z-dpo)) = s*P(s^2)
      auto fval = [&](float z) {
        float s = __builtin_amdgcn_sinf(0.5f * (z - dpo));   // revolutions
        float t = s * s;
        return s * fmaf(t, fmaf(t, fmaf(t, -9.142857142857142f, 19.2f),
                                -13.333333333333334f), 4.0f);
      };

      float q;
      if (five_tap) {
        int u0 = u > 0 ? u - 1 : 0;
        int u2 = u < 511 ? u + 1 : 511;
        int v0 = v > 0 ? v - 1 : 0;
        int v2 = v < 511 ? v + 1 : 511;
        float zT = z_map[base + (v0 << 9) + u];
        float zL = zrC[u0];
        float zR = zrC[u2];
        float zB = z_map[base + (v2 << 9) + u];
        float wuL = (u > 0)   ? w1 : 0.0f;
        float wuR = (u < 511) ? w1 : 0.0f;
        float wvT = (v > 0)   ? w1 : 0.0f;
        float wvB = (v < 511) ? w1 : 0.0f;
        float qs = w0 * fval(zg);
        qs = fmaf(wvT, fval(zT), qs);
        qs = fmaf(wvB, fval(zB), qs);
        qs = fmaf(wuL, fval(zL), qs);
        qs = fmaf(wuR, fval(zR), qs);
        q = TWO_OVER_PI * (w0 * qs);
      } else {
        // 1-tap mode: side weights < 5.6e-3 dropped (validated R13)
        q = TWO_OVER_PI * (w0sq * fval(zg));
      }

      float diff = fmaxf(dd - zg, 0.0f);
      hard_out = mk * ((diff > 0.008f) ? 0.0f : 1.0f);
      float qc = fminf(fmaxf(q, -CLB), CLB) / CLB;
      float sf = 0.5f * (qc + 1.0f);
      soft_out = mk * fminf(fmaxf(sf, 0.0f), 1.0f);
    }
    out[base + p] = hard_out;
    out[(NL*NPIX) + base + p] = soft_out;
  }
}

extern "C" void kernel_launch(void* const* d_in, const int* in_sizes, int n_in,
                              void* d_out, int out_size, void* d_ws, size_t ws_size,
                              hipStream_t stream) {
  (void)in_sizes; (void)n_in; (void)out_size; (void)ws_size;
  const float* depth = (const float*)d_in[0];
  const float* als   = (const float*)d_in[1];
  const float* mask  = (const float*)d_in[2];
  const float* z_map = (const float*)d_in[3];
  float* out = (float*)d_out;
  float* lp = (float*)d_ws;                       // 16 lights x 16 floats = 1KB
  // constants in double, replicating numpy, then rounded to f32
  double TANH = tan(2.0*atan(0.5*36.0/50.0)/2.0);
  double NEARc = 2.7 - sqrt(2.0)*2.7*TANH;
  double FARc  = 2.7 + sqrt(2.0)*2.7*TANH;
  float ozf = (float)(-2.0/(FARc-NEARc));
  float owf = (float)((-(FARc+NEARc))/(FARc-NEARc));
  float tanhf_ = (float)TANH;

  setup_kernel<<<1, 64, 0, stream>>>(als, lp);
  fused_kernel<<<(NL/2)*NPIX/128, 128, 0, stream>>>(depth, mask, z_map, lp,
                                                    out, tanhf_, ozf, owf);
}